// Round 7
// baseline (500.232 us; speedup 1.0000x reference)
//
#include <hip/hip_runtime.h>

// CRF-RNN forward, MI355X. P and T live in bf16 QUAD-PLANAR layout
// [4 quad-planes][512][512][4ch] (8 B = ushort4 per pixel-quad), giving fully
// contiguous 8B/lane access for streaming, staging and stencil reads.
// U (unaries) and all accumulation stay f32. Per iteration:
//   k_convv   : vertical 19-tap gaussian, 4 outputs/thread, bf16 in/out
//   k_combine : LDS-tiled hconv + 5x5 bilateral + channel mix + q + softmax

constexpr int H = 512, W = 512;
constexpr int HW = H * W;
constexpr int NUM_ITERS = 5;
constexpr float INV2A = 1.0f / (2.0f * 160.0f * 160.0f);
constexpr float INV2B = 1.0f / (2.0f * 3.0f * 3.0f);

// workspace layout (float offsets)
constexpr size_t PLANAR_F = (size_t)HW * 8;           // bf16 planar buf in floats
constexpr size_t OFF_U  = 0;                          // unaries f32 (H,W,16)
constexpr size_t OFF_PA = OFF_U  + (size_t)HW * 16;   // P buf A, bf16 planar
constexpr size_t OFF_PB = OFF_PA + PLANAR_F;          // P buf B, bf16 planar
constexpr size_t OFF_T  = OFF_PB + PLANAR_F;          // T, bf16 planar
constexpr size_t OFF_SV = OFF_T  + PLANAR_F;          // 1D spatial-norm [512]
constexpr size_t OFF_KG = OFF_SV + 512;               // gauss taps [19] pad 32
constexpr size_t OFF_M1 = OFF_KG + 32;                // C@Sw 16x16 row-major
constexpr size_t OFF_M2 = OFF_M1 + 256;               // C@Bw 16x16 row-major
// total ~10.49M floats = 42 MB

// ------------------------------------------------------------- bf16 helpers
__device__ inline void unpack2(unsigned u, float& lo, float& hi) {
    lo = __uint_as_float(u << 16);
    hi = __uint_as_float(u & 0xFFFF0000u);
}
__device__ inline unsigned short f2bf(float x) {
    unsigned u = __float_as_uint(x);
    return (unsigned short)((u + 0x7FFFu + ((u >> 16) & 1u)) >> 16);
}
__device__ inline unsigned pack2(float a, float b) {
    return (unsigned)f2bf(a) | ((unsigned)f2bf(b) << 16);
}
// bijective XCD swizzle (grid size divisible by 8)
__device__ inline int swz8(int b, int per) { return (b & 7) * per + (b >> 3); }

// ---------------------------------------------------------------- init tables
__global__ void k_init(const float* __restrict__ Sw, const float* __restrict__ Bw,
                       const float* __restrict__ Cm, float* __restrict__ ws) {
    __shared__ float kg[19];
    int tid = threadIdx.x;
    if (tid < 19) { int t = tid - 9; kg[tid] = expf(-(float)(t * t) / 18.0f); }
    __syncthreads();
    if (tid < 19) ws[OFF_KG + tid] = kg[tid];
    if (tid < 512) {
        float s = 0.0f;
        for (int t = -9; t <= 9; ++t) {
            int yy = tid + t;
            if (yy >= 0 && yy < 512) s += kg[t + 9];
        }
        ws[OFF_SV + tid] = s;
    }
    if (tid < 256) {
        int r = tid >> 4, c = tid & 15;
        float a = 0.0f, b = 0.0f;
        for (int k = 0; k < 16; ++k) {
            float cv = Cm[r * 16 + k];
            a += cv * Sw[k * 16 + c];
            b += cv * Bw[k * 16 + c];
        }
        ws[OFF_M1 + tid] = a;
        ws[OFF_M2 + tid] = b;
    }
}

// ------------------- unaries (to f32 HWD) + fused softmax -> P_A (bf16 planar)
__global__ __launch_bounds__(256) void k_prep(const float* __restrict__ ub,
                                              const float* __restrict__ ug,
                                              const float* __restrict__ pbw,
                                              const float* __restrict__ pgw,
                                              float* __restrict__ ws) {
    int pix = blockIdx.x * 256 + threadIdx.x;
    float bw = pbw[0], gw = pgw[0];

    float u[16];
#pragma unroll
    for (int i = 0; i < 16; ++i)
        u[i] = ub[(size_t)i * HW + pix] * bw + ug[(size_t)i * HW + pix] * gw;

    float4* U4 = (float4*)(ws + OFF_U);
#pragma unroll
    for (int j = 0; j < 4; ++j)
        U4[(size_t)pix * 4 + j] = make_float4(u[4 * j], u[4 * j + 1], u[4 * j + 2], u[4 * j + 3]);

    float m = u[0];
#pragma unroll
    for (int i = 1; i < 16; ++i) m = fmaxf(m, u[i]);
    float sum = 0.0f;
#pragma unroll
    for (int i = 0; i < 16; ++i) { u[i] = __expf(u[i] - m); sum += u[i]; }
    float inv = 1.0f / sum;
    uint2* PA = (uint2*)(ws + OFF_PA);
#pragma unroll
    for (int q = 0; q < 4; ++q)
        PA[(size_t)q * HW + pix] = make_uint2(pack2(u[4 * q] * inv, u[4 * q + 1] * inv),
                                              pack2(u[4 * q + 2] * inv, u[4 * q + 3] * inv));
}

// ---------------- vertical 19-tap gaussian, planar bf16, 4 outputs/thread
__global__ __launch_bounds__(256) void k_convv(const float* __restrict__ ws,
                                               const uint2* __restrict__ P,
                                               uint2* __restrict__ T) {
    int b = swz8(blockIdx.x, 128);
    int gtid = b * 256 + threadIdx.x;
    int x  = gtid & 511;
    int q  = (gtid >> 9) & 3;
    int yb = (gtid >> 11) << 2;               // 4 output rows per thread

    float kg[19];
#pragma unroll
    for (int t = 0; t < 19; ++t) kg[t] = ws[OFF_KG + t];

    const uint2* Pq = P + (size_t)q * HW;
    float4 acc[4];
#pragma unroll
    for (int k = 0; k < 4; ++k) acc[k] = make_float4(0.f, 0.f, 0.f, 0.f);

#pragma unroll
    for (int t = 0; t < 22; ++t) {
        int yy = yb + t - 9;
        float4 p = make_float4(0.f, 0.f, 0.f, 0.f);
        if ((unsigned)yy < (unsigned)H) {
            uint2 v = Pq[(size_t)yy * W + x];
            unpack2(v.x, p.x, p.y);
            unpack2(v.y, p.z, p.w);
        }
        int k0 = (t - 18 > 0) ? t - 18 : 0;
        int k1 = (t < 3) ? t : 3;
#pragma unroll
        for (int k = k0; k <= k1; ++k) {
            float w = kg[t - k];
            acc[k].x += w * p.x; acc[k].y += w * p.y;
            acc[k].z += w * p.z; acc[k].w += w * p.w;
        }
    }
    uint2* Tq = T + (size_t)q * HW;
#pragma unroll
    for (int k = 0; k < 4; ++k)
        Tq[(size_t)(yb + k) * W + x] = make_uint2(pack2(acc[k].x, acc[k].y),
                                                  pack2(acc[k].z, acc[k].w));
}

// --- fused: hconv + /snorm + bilateral + /bnorm + channel mix + q (+ softmax)
// tile 64x4 outputs / 256 threads; planar bf16 LDS, all accesses contiguous.
__global__ __launch_bounds__(256, 4) void k_combine(const float* __restrict__ ws,
                                                    const float* __restrict__ img,
                                                    const uint2* __restrict__ Tsrc,
                                                    const uint2* __restrict__ Psrc,
                                                    uint2* __restrict__ Pdst,
                                                    float4* __restrict__ outF,
                                                    int do_softmax) {
    __shared__ uint2 sT[4 * 4 * 82];    // [q][row 4][px 82]  10496 B
    __shared__ uint2 sP[4 * 8 * 68];    // [q][row 8][px 68]  17408 B
    __shared__ float sI[8 * 68 * 3];    //                     6528 B
    __shared__ float skg[19];
    __shared__ float sM1[256], sM2[256];

    int tid = threadIdx.x;
    int b = swz8(blockIdx.x, 128);
    int x0 = (b & 7) * 64;
    int y0 = (b >> 3) * 4;

    if (tid < 19) skg[tid] = ws[OFF_KG + tid];
    sM1[tid] = ws[OFF_M1 + tid];
    sM2[tid] = ws[OFF_M2 + tid];

    // stage T: 4 planes x 4 rows x 82 px (x-halo 9)
    for (int e = tid; e < 1312; e += 256) {
        int q = e / 328, rem = e - q * 328;
        int row = rem / 82, px = rem - row * 82;
        int gx = x0 - 9 + px;
        uint2 v = make_uint2(0u, 0u);
        if ((unsigned)gx < (unsigned)W)
            v = Tsrc[(size_t)q * HW + (size_t)(y0 + row) * W + gx];
        sT[e] = v;
    }
    // stage P: 4 planes x 8 rows x 68 px (halo 2)
    for (int e = tid; e < 2176; e += 256) {
        int q = e / 544, rem = e - q * 544;
        int row = rem / 68, px = rem - row * 68;
        int gx = x0 - 2 + px, gy = y0 - 2 + row;
        uint2 v = make_uint2(0u, 0u);
        if ((unsigned)gx < (unsigned)W && (unsigned)gy < (unsigned)H)
            v = Psrc[(size_t)q * HW + (size_t)gy * W + gx];
        sP[e] = v;
    }
    // stage rgb: 8 rows x 68 px
    for (int e = tid; e < 544; e += 256) {
        int row = e / 68, px = e - row * 68;
        int gx = x0 - 2 + px, gy = y0 - 2 + row;
        float r = 0.f, g = 0.f, bb = 0.f;
        if ((unsigned)gx < (unsigned)W && (unsigned)gy < (unsigned)H) {
            const float* ip = img + ((size_t)gy * W + gx) * 3;
            r = ip[0]; g = ip[1]; bb = ip[2];
        }
        sI[e * 3 + 0] = r; sI[e * 3 + 1] = g; sI[e * 3 + 2] = bb;
    }
    __syncthreads();

    int ly = tid >> 6, lx = tid & 63;
    int y = y0 + ly, x = x0 + lx;

    // horizontal 19-tap conv from LDS (bf16 planar)
    float sp[16];
#pragma unroll
    for (int i = 0; i < 16; ++i) sp[i] = 0.0f;
#pragma unroll
    for (int t = 0; t < 19; ++t) {
        float k = skg[t];
        int base = ly * 82 + lx + t;
#pragma unroll
        for (int q = 0; q < 4; ++q) {
            uint2 v = sT[q * 328 + base];
            float a, bq, c, d;
            unpack2(v.x, a, bq); unpack2(v.y, c, d);
            sp[4 * q + 0] += k * a; sp[4 * q + 1] += k * bq;
            sp[4 * q + 2] += k * c; sp[4 * q + 3] += k * d;
        }
    }
    float inv_sn = 1.0f / (ws[OFF_SV + y] * ws[OFF_SV + x]);
#pragma unroll
    for (int i = 0; i < 16; ++i) sp[i] *= inv_sn;

    // 5x5 bilateral from LDS (norm accumulated on the fly)
    float bl[16];
#pragma unroll
    for (int i = 0; i < 16; ++i) bl[i] = 0.0f;
    float bn = 0.0f;
    const float* ic = &sI[((ly + 2) * 68 + lx + 2) * 3];
    float r0 = ic[0], g0 = ic[1], b0 = ic[2];
#pragma unroll
    for (int dy = 0; dy < 5; ++dy) {
        int gy = y + dy - 2;
        bool vy = (unsigned)gy < (unsigned)H;
#pragma unroll
        for (int dx = 0; dx < 5; ++dx) {
            int gx = x + dx - 2;
            const float* ip = &sI[((ly + dy) * 68 + lx + dx) * 3];
            float dr = r0 - ip[0], dg = g0 - ip[1], db = b0 - ip[2];
            float wgt = __expf(-(float)((dy - 2) * (dy - 2) + (dx - 2) * (dx - 2)) * INV2A
                               - (dr * dr + dg * dg + db * db) * INV2B);
            if (!(vy && (unsigned)gx < (unsigned)W)) wgt = 0.0f;
            bn += wgt;
            int base = (ly + dy) * 68 + lx + dx;
#pragma unroll
            for (int q = 0; q < 4; ++q) {
                uint2 v = sP[q * 544 + base];
                float a, bq, c, d;
                unpack2(v.x, a, bq); unpack2(v.y, c, d);
                bl[4 * q + 0] += wgt * a; bl[4 * q + 1] += wgt * bq;
                bl[4 * q + 2] += wgt * c; bl[4 * q + 3] += wgt * d;
            }
        }
    }
    float inv_bn = 1.0f / bn;
#pragma unroll
    for (int i = 0; i < 16; ++i) bl[i] *= inv_bn;

    // q = U - M1@sp - M2@bl
    size_t pix = (size_t)y * W + x;
    const float4* U4 = (const float4*)(ws + OFF_U);
    float qn[16];
#pragma unroll
    for (int i = 0; i < 16; ++i) {
        float acc = 0.0f;
#pragma unroll
        for (int j4 = 0; j4 < 4; ++j4) {
            float4 m1 = *(const float4*)&sM1[i * 16 + j4 * 4];
            float4 m2 = *(const float4*)&sM2[i * 16 + j4 * 4];
            acc += m1.x * sp[4 * j4 + 0] + m1.y * sp[4 * j4 + 1]
                 + m1.z * sp[4 * j4 + 2] + m1.w * sp[4 * j4 + 3];
            acc += m2.x * bl[4 * j4 + 0] + m2.y * bl[4 * j4 + 1]
                 + m2.z * bl[4 * j4 + 2] + m2.w * bl[4 * j4 + 3];
        }
        qn[i] = -acc;
    }
#pragma unroll
    for (int j = 0; j < 4; ++j) {
        float4 u = U4[pix * 4 + j];
        qn[4 * j + 0] += u.x; qn[4 * j + 1] += u.y;
        qn[4 * j + 2] += u.z; qn[4 * j + 3] += u.w;
    }

    if (do_softmax) {
        float m = qn[0];
#pragma unroll
        for (int i = 1; i < 16; ++i) m = fmaxf(m, qn[i]);
        float sum = 0.0f;
#pragma unroll
        for (int i = 0; i < 16; ++i) { qn[i] = __expf(qn[i] - m); sum += qn[i]; }
        float inv = 1.0f / sum;
#pragma unroll
        for (int q = 0; q < 4; ++q)
            Pdst[(size_t)q * HW + pix] = make_uint2(pack2(qn[4 * q] * inv, qn[4 * q + 1] * inv),
                                                    pack2(qn[4 * q + 2] * inv, qn[4 * q + 3] * inv));
    } else {
#pragma unroll
        for (int j = 0; j < 4; ++j)
            outF[pix * 4 + j] = make_float4(qn[4 * j], qn[4 * j + 1], qn[4 * j + 2], qn[4 * j + 3]);
    }
}

// --------------------------------------------------------------------- launcher
extern "C" void kernel_launch(void* const* d_in, const int* in_sizes, int n_in,
                              void* d_out, int out_size, void* d_ws, size_t ws_size,
                              hipStream_t stream) {
    const float* img = (const float*)d_in[0];
    const float* ub  = (const float*)d_in[1];
    const float* ug  = (const float*)d_in[2];
    const float* Sw  = (const float*)d_in[3];
    const float* Bw  = (const float*)d_in[4];
    const float* Cm  = (const float*)d_in[5];
    const float* pbw = (const float*)d_in[6];
    const float* pgw = (const float*)d_in[7];
    float* ws  = (float*)d_ws;
    float* out = (float*)d_out;

    uint2* PA = (uint2*)(ws + OFF_PA);
    uint2* PB = (uint2*)(ws + OFF_PB);
    uint2* T  = (uint2*)(ws + OFF_T);

    k_init<<<1, 512, 0, stream>>>(Sw, Bw, Cm, ws);
    k_prep<<<HW / 256, 256, 0, stream>>>(ub, ug, pbw, pgw, ws);

    for (int it = 0; it < NUM_ITERS; ++it) {
        uint2* Ps = (it & 1) ? PB : PA;
        uint2* Pd = (it & 1) ? PA : PB;
        k_convv<<<1024, 256, 0, stream>>>(ws, Ps, T);
        if (it < NUM_ITERS - 1)
            k_combine<<<1024, 256, 0, stream>>>(ws, img, T, Ps, Pd, nullptr, 1);
        else
            k_combine<<<1024, 256, 0, stream>>>(ws, img, T, Ps, nullptr, (float4*)out, 0);
    }
}

// Round 9
// 303.585 us; speedup vs baseline: 1.6477x; 1.6477x over previous
//
#include <hip/hip_runtime.h>

// CRF-RNN forward, MI355X. P and T in bf16 QUAD-PLANAR layout
// [4 quad-planes][512][512][4ch] (8 B = uint2 per pixel-quad): contiguous
// 8B/lane access for streaming, staging and stencil reads. U and all
// accumulation stay f32. Per iteration:
//   k_convv   : vertical 19-tap gaussian, 4 outputs/thread, bf16 in/out
//   k_combine : LDS-tiled hconv + 5x5 bilateral + channel mix + q + softmax
// NOTE: no min-waves launch bound on k_combine — __launch_bounds__(256,4)
// made LLVM target 8 waves/EU (64 VGPR) and spill to scratch: 193 MB/dispatch
// of scratch writes (rocprof round 7). Let the allocator pick.

constexpr int H = 512, W = 512;
constexpr int HW = H * W;
constexpr int NUM_ITERS = 5;
constexpr float INV2A = 1.0f / (2.0f * 160.0f * 160.0f);
constexpr float INV2B = 1.0f / (2.0f * 3.0f * 3.0f);

// workspace layout (float offsets)
constexpr size_t PLANAR_F = (size_t)HW * 8;           // bf16 planar buf in floats
constexpr size_t OFF_U  = 0;                          // unaries f32 (H,W,16)
constexpr size_t OFF_PA = OFF_U  + (size_t)HW * 16;   // P buf A, bf16 planar
constexpr size_t OFF_PB = OFF_PA + PLANAR_F;          // P buf B, bf16 planar
constexpr size_t OFF_T  = OFF_PB + PLANAR_F;          // T, bf16 planar
constexpr size_t OFF_SV = OFF_T  + PLANAR_F;          // 1D spatial-norm [512]
constexpr size_t OFF_KG = OFF_SV + 512;               // gauss taps [19] pad 32
constexpr size_t OFF_M1 = OFF_KG + 32;                // C@Sw 16x16 row-major
constexpr size_t OFF_M2 = OFF_M1 + 256;               // C@Bw 16x16 row-major

// ------------------------------------------------------------- bf16 helpers
__device__ inline void unpack2(unsigned u, float& lo, float& hi) {
    lo = __uint_as_float(u << 16);
    hi = __uint_as_float(u & 0xFFFF0000u);
}
__device__ inline unsigned short f2bf(float x) {
    unsigned u = __float_as_uint(x);
    return (unsigned short)((u + 0x7FFFu + ((u >> 16) & 1u)) >> 16);
}
__device__ inline unsigned pack2(float a, float b) {
    return (unsigned)f2bf(a) | ((unsigned)f2bf(b) << 16);
}
// bijective XCD swizzle (grid size divisible by 8)
__device__ inline int swz8(int b, int per) { return (b & 7) * per + (b >> 3); }

// ---------------------------------------------------------------- init tables
__global__ void k_init(const float* __restrict__ Sw, const float* __restrict__ Bw,
                       const float* __restrict__ Cm, float* __restrict__ ws) {
    __shared__ float kg[19];
    int tid = threadIdx.x;
    if (tid < 19) { int t = tid - 9; kg[tid] = expf(-(float)(t * t) / 18.0f); }
    __syncthreads();
    if (tid < 19) ws[OFF_KG + tid] = kg[tid];
    if (tid < 512) {
        float s = 0.0f;
        for (int t = -9; t <= 9; ++t) {
            int yy = tid + t;
            if (yy >= 0 && yy < 512) s += kg[t + 9];
        }
        ws[OFF_SV + tid] = s;
    }
    if (tid < 256) {
        int r = tid >> 4, c = tid & 15;
        float a = 0.0f, b = 0.0f;
        for (int k = 0; k < 16; ++k) {
            float cv = Cm[r * 16 + k];
            a += cv * Sw[k * 16 + c];
            b += cv * Bw[k * 16 + c];
        }
        ws[OFF_M1 + tid] = a;
        ws[OFF_M2 + tid] = b;
    }
}

// ------------------- unaries (to f32 HWD) + fused softmax -> P_A (bf16 planar)
__global__ __launch_bounds__(256) void k_prep(const float* __restrict__ ub,
                                              const float* __restrict__ ug,
                                              const float* __restrict__ pbw,
                                              const float* __restrict__ pgw,
                                              float* __restrict__ ws) {
    int pix = blockIdx.x * 256 + threadIdx.x;
    float bw = pbw[0], gw = pgw[0];

    float u[16];
#pragma unroll
    for (int i = 0; i < 16; ++i)
        u[i] = ub[(size_t)i * HW + pix] * bw + ug[(size_t)i * HW + pix] * gw;

    float4* U4 = (float4*)(ws + OFF_U);
#pragma unroll
    for (int j = 0; j < 4; ++j)
        U4[(size_t)pix * 4 + j] = make_float4(u[4 * j], u[4 * j + 1], u[4 * j + 2], u[4 * j + 3]);

    float m = u[0];
#pragma unroll
    for (int i = 1; i < 16; ++i) m = fmaxf(m, u[i]);
    float sum = 0.0f;
#pragma unroll
    for (int i = 0; i < 16; ++i) { u[i] = __expf(u[i] - m); sum += u[i]; }
    float inv = 1.0f / sum;
    uint2* PA = (uint2*)(ws + OFF_PA);
#pragma unroll
    for (int q = 0; q < 4; ++q)
        PA[(size_t)q * HW + pix] = make_uint2(pack2(u[4 * q] * inv, u[4 * q + 1] * inv),
                                              pack2(u[4 * q + 2] * inv, u[4 * q + 3] * inv));
}

// ---------------- vertical 19-tap gaussian, planar bf16, 4 outputs/thread
__global__ __launch_bounds__(256) void k_convv(const float* __restrict__ ws,
                                               const uint2* __restrict__ P,
                                               uint2* __restrict__ T) {
    int b = swz8(blockIdx.x, 128);
    int gtid = b * 256 + threadIdx.x;
    int x  = gtid & 511;
    int q  = (gtid >> 9) & 3;
    int yb = (gtid >> 11) << 2;               // 4 output rows per thread

    float kg[19];
#pragma unroll
    for (int t = 0; t < 19; ++t) kg[t] = ws[OFF_KG + t];

    const uint2* Pq = P + (size_t)q * HW;
    float4 acc[4];
#pragma unroll
    for (int k = 0; k < 4; ++k) acc[k] = make_float4(0.f, 0.f, 0.f, 0.f);

#pragma unroll
    for (int t = 0; t < 22; ++t) {
        int yy = yb + t - 9;
        float4 p = make_float4(0.f, 0.f, 0.f, 0.f);
        if ((unsigned)yy < (unsigned)H) {
            uint2 v = Pq[(size_t)yy * W + x];
            unpack2(v.x, p.x, p.y);
            unpack2(v.y, p.z, p.w);
        }
        int k0 = (t - 18 > 0) ? t - 18 : 0;
        int k1 = (t < 3) ? t : 3;
#pragma unroll
        for (int k = k0; k <= k1; ++k) {
            float w = kg[t - k];
            acc[k].x += w * p.x; acc[k].y += w * p.y;
            acc[k].z += w * p.z; acc[k].w += w * p.w;
        }
    }
    uint2* Tq = T + (size_t)q * HW;
#pragma unroll
    for (int k = 0; k < 4; ++k)
        Tq[(size_t)(yb + k) * W + x] = make_uint2(pack2(acc[k].x, acc[k].y),
                                                  pack2(acc[k].z, acc[k].w));
}

// --- fused: hconv (+M1 fold) + bilateral (+M2 fold) + U + (softmax | store)
// tile 64x4 outputs / 256 threads; planar bf16 LDS, all accesses contiguous.
// Matmuls folded right after each stencil so sp[] dies before bl[] lives:
// peak accumulator pressure 32 f32 instead of 48.
__global__ __launch_bounds__(256) void k_combine(const float* __restrict__ ws,
                                                 const float* __restrict__ img,
                                                 const uint2* __restrict__ Tsrc,
                                                 const uint2* __restrict__ Psrc,
                                                 uint2* __restrict__ Pdst,
                                                 float4* __restrict__ outF,
                                                 int do_softmax) {
    __shared__ uint2 sT[4 * 4 * 82];    // [q][row 4][px 82]  10496 B
    __shared__ uint2 sP[4 * 8 * 68];    // [q][row 8][px 68]  17408 B
    __shared__ float sI[8 * 68 * 3];    //                     6528 B
    __shared__ float skg[19];
    __shared__ float sM1[256], sM2[256];

    int tid = threadIdx.x;
    int b = swz8(blockIdx.x, 128);
    int x0 = (b & 7) * 64;
    int y0 = (b >> 3) * 4;

    if (tid < 19) skg[tid] = ws[OFF_KG + tid];
    sM1[tid] = ws[OFF_M1 + tid];
    sM2[tid] = ws[OFF_M2 + tid];

    // stage T: 4 planes x 4 rows x 82 px (x-halo 9)
    for (int e = tid; e < 1312; e += 256) {
        int q = e / 328, rem = e - q * 328;
        int row = rem / 82, px = rem - row * 82;
        int gx = x0 - 9 + px;
        uint2 v = make_uint2(0u, 0u);
        if ((unsigned)gx < (unsigned)W)
            v = Tsrc[(size_t)q * HW + (size_t)(y0 + row) * W + gx];
        sT[e] = v;
    }
    // stage P: 4 planes x 8 rows x 68 px (halo 2)
    for (int e = tid; e < 2176; e += 256) {
        int q = e / 544, rem = e - q * 544;
        int row = rem / 68, px = rem - row * 68;
        int gx = x0 - 2 + px, gy = y0 - 2 + row;
        uint2 v = make_uint2(0u, 0u);
        if ((unsigned)gx < (unsigned)W && (unsigned)gy < (unsigned)H)
            v = Psrc[(size_t)q * HW + (size_t)gy * W + gx];
        sP[e] = v;
    }
    // stage rgb: 8 rows x 68 px
    for (int e = tid; e < 544; e += 256) {
        int row = e / 68, px = e - row * 68;
        int gx = x0 - 2 + px, gy = y0 - 2 + row;
        float r = 0.f, g = 0.f, bb = 0.f;
        if ((unsigned)gx < (unsigned)W && (unsigned)gy < (unsigned)H) {
            const float* ip = img + ((size_t)gy * W + gx) * 3;
            r = ip[0]; g = ip[1]; bb = ip[2];
        }
        sI[e * 3 + 0] = r; sI[e * 3 + 1] = g; sI[e * 3 + 2] = bb;
    }
    __syncthreads();

    int ly = tid >> 6, lx = tid & 63;
    int y = y0 + ly, x = x0 + lx;

    float qn[16];

    {   // horizontal 19-tap conv from LDS, then fold qn = -(M1 @ sp)
        float sp[16];
#pragma unroll
        for (int i = 0; i < 16; ++i) sp[i] = 0.0f;
#pragma unroll
        for (int t = 0; t < 19; ++t) {
            float k = skg[t];
            int base = ly * 82 + lx + t;
#pragma unroll
            for (int q = 0; q < 4; ++q) {
                uint2 v = sT[q * 328 + base];
                float a, bq, c, d;
                unpack2(v.x, a, bq); unpack2(v.y, c, d);
                sp[4 * q + 0] += k * a; sp[4 * q + 1] += k * bq;
                sp[4 * q + 2] += k * c; sp[4 * q + 3] += k * d;
            }
        }
        float inv_sn = 1.0f / (ws[OFF_SV + y] * ws[OFF_SV + x]);
#pragma unroll
        for (int i = 0; i < 16; ++i) sp[i] *= inv_sn;
#pragma unroll
        for (int i = 0; i < 16; ++i) {
            float acc = 0.0f;
#pragma unroll
            for (int j4 = 0; j4 < 4; ++j4) {
                float4 m1 = *(const float4*)&sM1[i * 16 + j4 * 4];
                acc += m1.x * sp[4 * j4 + 0] + m1.y * sp[4 * j4 + 1]
                     + m1.z * sp[4 * j4 + 2] + m1.w * sp[4 * j4 + 3];
            }
            qn[i] = -acc;
        }
    }

    {   // 5x5 bilateral from LDS, then fold qn -= M2 @ bl
        float bl[16];
#pragma unroll
        for (int i = 0; i < 16; ++i) bl[i] = 0.0f;
        float bn = 0.0f;
        const float* ic = &sI[((ly + 2) * 68 + lx + 2) * 3];
        float r0 = ic[0], g0 = ic[1], b0 = ic[2];
#pragma unroll
        for (int dy = 0; dy < 5; ++dy) {
            int gy = y + dy - 2;
            bool vy = (unsigned)gy < (unsigned)H;
#pragma unroll
            for (int dx = 0; dx < 5; ++dx) {
                int gx = x + dx - 2;
                const float* ip = &sI[((ly + dy) * 68 + lx + dx) * 3];
                float dr = r0 - ip[0], dg = g0 - ip[1], db = b0 - ip[2];
                float wgt = __expf(-(float)((dy - 2) * (dy - 2) + (dx - 2) * (dx - 2)) * INV2A
                                   - (dr * dr + dg * dg + db * db) * INV2B);
                if (!(vy && (unsigned)gx < (unsigned)W)) wgt = 0.0f;
                bn += wgt;
                int base = (ly + dy) * 68 + lx + dx;
#pragma unroll
                for (int q = 0; q < 4; ++q) {
                    uint2 v = sP[q * 544 + base];
                    float a, bq, c, d;
                    unpack2(v.x, a, bq); unpack2(v.y, c, d);
                    bl[4 * q + 0] += wgt * a; bl[4 * q + 1] += wgt * bq;
                    bl[4 * q + 2] += wgt * c; bl[4 * q + 3] += wgt * d;
                }
            }
        }
        float inv_bn = 1.0f / bn;
#pragma unroll
        for (int i = 0; i < 16; ++i) bl[i] *= inv_bn;
#pragma unroll
        for (int i = 0; i < 16; ++i) {
            float acc = 0.0f;
#pragma unroll
            for (int j4 = 0; j4 < 4; ++j4) {
                float4 m2 = *(const float4*)&sM2[i * 16 + j4 * 4];
                acc += m2.x * bl[4 * j4 + 0] + m2.y * bl[4 * j4 + 1]
                     + m2.z * bl[4 * j4 + 2] + m2.w * bl[4 * j4 + 3];
            }
            qn[i] -= acc;
        }
    }

    size_t pix = (size_t)y * W + x;
    const float4* U4 = (const float4*)(ws + OFF_U);
#pragma unroll
    for (int j = 0; j < 4; ++j) {
        float4 u = U4[pix * 4 + j];
        qn[4 * j + 0] += u.x; qn[4 * j + 1] += u.y;
        qn[4 * j + 2] += u.z; qn[4 * j + 3] += u.w;
    }

    if (do_softmax) {
        float m = qn[0];
#pragma unroll
        for (int i = 1; i < 16; ++i) m = fmaxf(m, qn[i]);
        float sum = 0.0f;
#pragma unroll
        for (int i = 0; i < 16; ++i) { qn[i] = __expf(qn[i] - m); sum += qn[i]; }
        float inv = 1.0f / sum;
#pragma unroll
        for (int q = 0; q < 4; ++q)
            Pdst[(size_t)q * HW + pix] = make_uint2(pack2(qn[4 * q] * inv, qn[4 * q + 1] * inv),
                                                    pack2(qn[4 * q + 2] * inv, qn[4 * q + 3] * inv));
    } else {
#pragma unroll
        for (int j = 0; j < 4; ++j)
            outF[pix * 4 + j] = make_float4(qn[4 * j], qn[4 * j + 1], qn[4 * j + 2], qn[4 * j + 3]);
    }
}

// --------------------------------------------------------------------- launcher
extern "C" void kernel_launch(void* const* d_in, const int* in_sizes, int n_in,
                              void* d_out, int out_size, void* d_ws, size_t ws_size,
                              hipStream_t stream) {
    const float* img = (const float*)d_in[0];
    const float* ub  = (const float*)d_in[1];
    const float* ug  = (const float*)d_in[2];
    const float* Sw  = (const float*)d_in[3];
    const float* Bw  = (const float*)d_in[4];
    const float* Cm  = (const float*)d_in[5];
    const float* pbw = (const float*)d_in[6];
    const float* pgw = (const float*)d_in[7];
    float* ws  = (float*)d_ws;
    float* out = (float*)d_out;

    uint2* PA = (uint2*)(ws + OFF_PA);
    uint2* PB = (uint2*)(ws + OFF_PB);
    uint2* T  = (uint2*)(ws + OFF_T);

    k_init<<<1, 512, 0, stream>>>(Sw, Bw, Cm, ws);
    k_prep<<<HW / 256, 256, 0, stream>>>(ub, ug, pbw, pgw, ws);

    for (int it = 0; it < NUM_ITERS; ++it) {
        uint2* Ps = (it & 1) ? PB : PA;
        uint2* Pd = (it & 1) ? PA : PB;
        k_convv<<<1024, 256, 0, stream>>>(ws, Ps, T);
        if (it < NUM_ITERS - 1)
            k_combine<<<1024, 256, 0, stream>>>(ws, img, T, Ps, Pd, nullptr, 1);
        else
            k_combine<<<1024, 256, 0, stream>>>(ws, img, T, Ps, nullptr, (float4*)out, 0);
    }
}